// Round 8
// baseline (4670.760 us; speedup 1.0000x reference)
//
#include <hip/hip_runtime.h>
#include <cstddef>
#include <cstdint>

#define BN_EPS 1e-5f

typedef _Float16 half8 __attribute__((ext_vector_type(8)));
typedef float f32x4v __attribute__((ext_vector_type(4)));

// pack fp32 (pre-scaled) into fp16 high/low split: v = h + l/2048
__device__ __forceinline__ unsigned split_pack(float v) {
    _Float16 h = (_Float16)v;
    float r = (v - (float)h) * 2048.0f;
    _Float16 l = (_Float16)r;
    unsigned short hu = __builtin_bit_cast(unsigned short, h);
    unsigned short lu = __builtin_bit_cast(unsigned short, l);
    return (unsigned)hu | ((unsigned)lu << 16);
}

// ===== prep: w[co][ci][kw] fp32 -> Wp[kw][co][CIPAD] packed u32, scaled x256
__global__ __launch_bounds__(256)
void prep_w(const float* __restrict__ w, unsigned* __restrict__ wp,
            int Cin, int KW, int CIPAD)
{
    int id = blockIdx.x * 256 + threadIdx.x;
    int total = KW * 768 * CIPAD;
    if (id >= total) return;
    int cip = id % CIPAD;
    int co  = (id / CIPAD) % 768;
    int kw  = id / (CIPAD * 768);
    float v = 0.0f;
    if (cip < Cin) v = w[((size_t)co * Cin + cip) * KW + kw];
    wp[id] = split_pack(v * 256.0f);
}

// ===== prep: mels[b][80][1024] fp32 -> melsT[b][1032][96] packed, scaled x16
__global__ __launch_bounds__(256)
void prep_mels(const float* __restrict__ mels, unsigned* __restrict__ mt)
{
    int id = blockIdx.x * 256 + threadIdx.x;
    if (id >= 32 * 1032 * 96) return;
    int c = id % 96;
    int t = (id / 96) % 1032;
    int b = id / (96 * 1032);
    float v = 0.0f;
    if (c < 80 && t < 1024) v = mels[((size_t)b * 80 + c) * 1024 + t];
    mt[id] = split_pack(v * 16.0f);
}

// ===== fp16x3-split MFMA conv + BN + ReLU =====================================
// Block 256 thr (4 waves), tile 128co x 128t, wave tile 64x64 (4x4 of 16x16x32).
// A = weights (scale 256), B = activations (scale 16), both packed h|l u32.
// result = (accHH + accCROSS/2048)/4096.
// C/D layout (m89-verified): col(n)=lane&15, row(m)=quad*4+reg.
// R8: conflict-free XOR-swizzled LDS planes (row stride 64B, phys chunk =
// chunk^(row&3)), double-buffered, 2-deep register prefetch, 1 barrier/chunk.
// EPI=0: write packed [t][768] u32; EPI=1 (conv5): write fp32 [co][TOUT].
template<int KW, int S, int P, int CIPAD, int TIN, int TSIN, int TOUT, int TSOUT, int EPI>
__global__ __launch_bounds__(256)
void conv_mfma(const unsigned* __restrict__ Xin, const unsigned* __restrict__ Wp,
               const float* __restrict__ gamma, const float* __restrict__ beta,
               const float* __restrict__ mean, const float* __restrict__ var,
               unsigned* __restrict__ Uout, float* __restrict__ Fout)
{
    constexpr int NCI = CIPAD / 32;
    constexpr int NC  = KW * NCI;          // >= 9 for all convs
    __shared__ unsigned smem[16896];       // 67584 B: bounce [128][132]; planes 2x32KB
    _Float16* sm = (_Float16*)smem;
    // per-buffer plane offsets (halfs): AH 0, AL 4096, BH 8192, BL 12288; buf stride 16384

    const int b   = blockIdx.z;
    const int co0 = blockIdx.x * 128;
    const int t0  = blockIdx.y * 128;
    const int tid = threadIdx.x;
    const int lane = tid & 63, wv = tid >> 6;
    const int quad = lane >> 4, l16 = lane & 15;
    const int wm = (wv & 1) * 64, wn = (wv >> 1) * 64;

    f32x4v accH[4][4] = {};
    f32x4v accX[4][4] = {};

    const int srow = tid >> 1;             // 0..127: row staged by this thread
    const int sh   = tid & 1;              // owns logical chunks {sh, sh+2}
    const unsigned* __restrict__ xb = Xin + (size_t)b * TSIN * CIPAD;

    uint4 rA[2][4], rB[2][4];

    auto loadAB = [&](int c, int s) {
        const int kw  = c / NCI;
        const int ci0 = (c % NCI) * 32;
        const unsigned* pA = Wp + (size_t)(kw * 768 + co0 + srow) * CIPAD + ci0;
        rA[s][0] = *(const uint4*)(pA + sh * 8);
        rA[s][1] = *(const uint4*)(pA + sh * 8 + 4);
        rA[s][2] = *(const uint4*)(pA + (sh + 2) * 8);
        rA[s][3] = *(const uint4*)(pA + (sh + 2) * 8 + 4);
        const int tp = (t0 + srow) * S + kw - P;
        rB[s][0] = rB[s][1] = rB[s][2] = rB[s][3] = make_uint4(0, 0, 0, 0);
        if ((unsigned)tp < (unsigned)TIN) {
            const unsigned* pB = xb + (size_t)tp * CIPAD + ci0;
            rB[s][0] = *(const uint4*)(pB + sh * 8);
            rB[s][1] = *(const uint4*)(pB + sh * 8 + 4);
            rB[s][2] = *(const uint4*)(pB + (sh + 2) * 8);
            rB[s][3] = *(const uint4*)(pB + (sh + 2) * 8 + 4);
        }
    };

    auto splitHL = [](uint4 a, uint4 b, uint4& h, uint4& l) {
        h.x = (a.x & 0xffffu) | (a.y << 16);
        h.y = (a.z & 0xffffu) | (a.w << 16);
        h.z = (b.x & 0xffffu) | (b.y << 16);
        h.w = (b.z & 0xffffu) | (b.w << 16);
        l.x = (a.x >> 16) | (a.y & 0xffff0000u);
        l.y = (a.z >> 16) | (a.w & 0xffff0000u);
        l.z = (b.x >> 16) | (b.y & 0xffff0000u);
        l.w = (b.z >> 16) | (b.w & 0xffff0000u);
    };

    auto storeAB = [&](int s, int pbuf) {
        const int base = pbuf * 16384 + srow * 32;
        const int pc1 = ((sh)     ^ (srow & 3)) * 8;
        const int pc2 = ((sh + 2) ^ (srow & 3)) * 8;
        uint4 h, l;
        splitHL(rA[s][0], rA[s][1], h, l);
        *(uint4*)(sm + base + 0    + pc1) = h;
        *(uint4*)(sm + base + 4096 + pc1) = l;
        splitHL(rA[s][2], rA[s][3], h, l);
        *(uint4*)(sm + base + 0    + pc2) = h;
        *(uint4*)(sm + base + 4096 + pc2) = l;
        splitHL(rB[s][0], rB[s][1], h, l);
        *(uint4*)(sm + base + 8192  + pc1) = h;
        *(uint4*)(sm + base + 12288 + pc1) = l;
        splitHL(rB[s][2], rB[s][3], h, l);
        *(uint4*)(sm + base + 8192  + pc2) = h;
        *(uint4*)(sm + base + 12288 + pc2) = l;
    };

    loadAB(0, 0);
    storeAB(0, 0);
    loadAB(1, 1);
    __syncthreads();

    int p = 0;
    for (int c = 0; c < NC; ++c) {
        const int base = p * 16384;
        if (c + 2 < NC) loadAB(c + 2, c & 1);          // issue early (other reg set)
        if (c + 1 < NC) storeAB((c + 1) & 1, p ^ 1);   // waits on loads(c+1) only

        half8 bh[4], bl[4];
#pragma unroll
        for (int nt = 0; nt < 4; ++nt) {
            int n = wn + nt * 16 + l16;
            int pc = (quad ^ (n & 3)) * 8;
            bh[nt] = *(const half8*)(sm + base + 8192  + n * 32 + pc);
            bl[nt] = *(const half8*)(sm + base + 12288 + n * 32 + pc);
        }
#pragma unroll
        for (int mt = 0; mt < 4; ++mt) {
            int m = wm + mt * 16 + l16;
            int pc = (quad ^ (m & 3)) * 8;
            half8 ah = *(const half8*)(sm + base + 0    + m * 32 + pc);
            half8 al = *(const half8*)(sm + base + 4096 + m * 32 + pc);
#pragma unroll
            for (int nt = 0; nt < 4; ++nt) {
                accH[mt][nt] = __builtin_amdgcn_mfma_f32_16x16x32_f16(ah, bh[nt], accH[mt][nt], 0, 0, 0);
                accX[mt][nt] = __builtin_amdgcn_mfma_f32_16x16x32_f16(ah, bl[nt], accX[mt][nt], 0, 0, 0);
                accX[mt][nt] = __builtin_amdgcn_mfma_f32_16x16x32_f16(al, bh[nt], accX[mt][nt], 0, 0, 0);
            }
        }
        __syncthreads();                               // reads of p & stores to p^1 done
        p ^= 1;
    }

    if constexpr (EPI == 0) {
        unsigned* bb = smem;                       // bounce: [t_local][co_local], stride 132
#pragma unroll
        for (int mt = 0; mt < 4; ++mt) {
#pragma unroll
            for (int r = 0; r < 4; ++r) {
                int mloc = wm + mt * 16 + quad * 4 + r;   // C/D row = co_local
                int co = co0 + mloc;
                float iv = gamma[co] / sqrtf(var[co] + BN_EPS);
                float sh2 = beta[co] - mean[co] * iv;
#pragma unroll
                for (int nt = 0; nt < 4; ++nt) {
                    float vf = (accH[mt][nt][r] + accX[mt][nt][r] * (1.0f / 2048.0f)) * (1.0f / 4096.0f);
                    float y = fmaf(vf, iv, sh2);
                    y = y > 0.0f ? y : 0.0f;
                    bb[(wn + nt * 16 + l16) * 132 + mloc] = split_pack(y * 16.0f);
                }
            }
        }
        __syncthreads();
        int tl = tid >> 1, seg = tid & 1;
        int t = t0 + tl;
        if (t < TOUT) {
            uint4* dst = (uint4*)(Uout + ((size_t)b * TSOUT + t) * 768 + co0 + seg * 64);
            const uint4* src = (const uint4*)(bb + tl * 132 + seg * 64);
#pragma unroll
            for (int i = 0; i < 16; ++i) dst[i] = src[i];
        }
    } else {
#pragma unroll
        for (int mt = 0; mt < 4; ++mt) {
#pragma unroll
            for (int r = 0; r < 4; ++r) {
                int co = co0 + wm + mt * 16 + quad * 4 + r;
                float iv = gamma[co] / sqrtf(var[co] + BN_EPS);
                float sh2 = beta[co] - mean[co] * iv;
                float* op = Fout + ((size_t)b * 768 + co) * TOUT;
#pragma unroll
                for (int nt = 0; nt < 4; ++nt) {
                    int t = t0 + wn + nt * 16 + l16;
                    if (t < TOUT) {
                        float vf = (accH[mt][nt][r] + accX[mt][nt][r] * (1.0f / 2048.0f)) * (1.0f / 4096.0f);
                        float y = fmaf(vf, iv, sh2);
                        op[t] = y > 0.0f ? y : 0.0f;
                    }
                }
            }
        }
    }
}

// ================= 1x1 conv (C=768 -> D=64) + bias, output z[b][t][d] =======
constexpr int TM = 64, TN = 64, TK = 16;

__global__ __launch_bounds__(256)
void conv1x1_bias_T(const float* __restrict__ in, const float* __restrict__ w,
                    const float* __restrict__ bias, float* __restrict__ z,
                    int Cin, int T)
{
    const int b   = blockIdx.z;
    const int t0  = blockIdx.y * TN;
    const int tid = threadIdx.x;

    __shared__ float As[TK][TM + 4];
    __shared__ float Bs[TK][TN + 4];

    float acc[4][4] = {};

    const int m0 = (tid & 15) * 4;
    const int n0 = (tid >> 4) * 4;

    const float* __restrict__ inb = in + (size_t)b * Cin * T;

    const int a_m = tid >> 4;
    const int a_k = tid & 15;
    const int b_k = tid >> 6;
    const int b_n = tid & 63;

    for (int kc = 0; kc < Cin; kc += TK) {
        __syncthreads();
#pragma unroll
        for (int i = 0; i < 4; ++i) {
            int m = a_m + 16 * i;
            As[a_k][m] = w[(size_t)m * Cin + kc + a_k];
        }
#pragma unroll
        for (int i = 0; i < 4; ++i) {
            int kk = b_k + 4 * i;
            int ci = kc + kk;
            int t  = t0 + b_n;
            Bs[kk][b_n] = (t < T) ? inb[(size_t)ci * T + t] : 0.0f;
        }
        __syncthreads();
#pragma unroll
        for (int kk = 0; kk < TK; ++kk) {
            float4 av = *reinterpret_cast<const float4*>(&As[kk][m0]);
            float4 bv = *reinterpret_cast<const float4*>(&Bs[kk][n0]);
            float am[4] = {av.x, av.y, av.z, av.w};
            float bn[4] = {bv.x, bv.y, bv.z, bv.w};
#pragma unroll
            for (int mi = 0; mi < 4; ++mi)
#pragma unroll
                for (int nj = 0; nj < 4; ++nj)
                    acc[mi][nj] = fmaf(am[mi], bn[nj], acc[mi][nj]);
        }
    }

    float4 bb = *reinterpret_cast<const float4*>(&bias[m0]);
    float bs[4] = {bb.x, bb.y, bb.z, bb.w};
#pragma unroll
    for (int nj = 0; nj < 4; ++nj) {
        int t = t0 + n0 + nj;
        if (t < T) {
            float4 v;
            v.x = acc[0][nj] + bs[0];
            v.y = acc[1][nj] + bs[1];
            v.z = acc[2][nj] + bs[2];
            v.w = acc[3][nj] + bs[3];
            *reinterpret_cast<float4*>(&z[((size_t)b * T + t) * 64 + m0]) = v;
        }
    }
}

// ============================== VQ kernels ==================================
__global__ __launch_bounds__(256)
void vq_e2(const float* __restrict__ emb, float* __restrict__ e2)
{
    int m = blockIdx.x * 256 + threadIdx.x;
    if (m < 512) {
        float s = 0.0f;
#pragma unroll
        for (int d = 0; d < 64; ++d) {
            float v = emb[(size_t)m * 64 + d];
            s = fmaf(v, v, s);
        }
        e2[m] = s;
    }
}

__global__ __launch_bounds__(64)
void vq_argmin(const float* __restrict__ z, const float* __restrict__ emb,
               const float* __restrict__ e2, int* __restrict__ idx,
               float* __restrict__ counts, int N)
{
    __shared__ float Es[64 * 64];
    const int tid = threadIdx.x;
    const int n   = blockIdx.x * 64 + tid;
    const bool act = n < N;

    float x[64];
    float x2 = 0.0f;
    if (act) {
        const float4* zp = reinterpret_cast<const float4*>(z + (size_t)n * 64);
#pragma unroll
        for (int i = 0; i < 16; ++i) {
            float4 v = zp[i];
            x[4 * i + 0] = v.x; x[4 * i + 1] = v.y;
            x[4 * i + 2] = v.z; x[4 * i + 3] = v.w;
        }
#pragma unroll
        for (int d = 0; d < 64; ++d) x2 = fmaf(x[d], x[d], x2);
    }

    float best = 3.4e38f;
    int   bi   = 0;
    for (int c = 0; c < 8; ++c) {
        __syncthreads();
        const float4* ep  = reinterpret_cast<const float4*>(emb + (size_t)c * 4096);
        float4*       esp = reinterpret_cast<float4*>(Es);
#pragma unroll
        for (int i = 0; i < 16; ++i) esp[tid + 64 * i] = ep[tid + 64 * i];
        __syncthreads();
        for (int r = 0; r < 64; ++r) {
            const float4* er = reinterpret_cast<const float4*>(&Es[r * 64]);
            float dot = 0.0f;
#pragma unroll
            for (int i = 0; i < 16; ++i) {
                float4 e4 = er[i];
                dot = fmaf(x[4 * i + 0], e4.x, dot);
                dot = fmaf(x[4 * i + 1], e4.y, dot);
                dot = fmaf(x[4 * i + 2], e4.z, dot);
                dot = fmaf(x[4 * i + 3], e4.w, dot);
            }
            float dist = (e2[c * 64 + r] + x2) - 2.0f * dot;  // reference op order
            if (dist < best) { best = dist; bi = c * 64 + r; }
        }
    }
    if (act) {
        idx[n] = bi;
        atomicAdd(&counts[bi], 1.0f);
    }
}

__global__ __launch_bounds__(256)
void vq_quant_loss(const float* __restrict__ z, const float* __restrict__ emb,
                   const int* __restrict__ idx, float* __restrict__ qout,
                   double* __restrict__ loss_sum, int Ntot)
{
    int g = blockIdx.x * 256 + threadIdx.x;
    float d2 = 0.0f;
    if (g < Ntot) {
        int n = g >> 6;
        int d = g & 63;
        float q  = emb[(size_t)idx[n] * 64 + d];
        float zv = z[g];
        qout[g] = zv + (q - zv);
        float diff = zv - q;
        d2 = diff * diff;
    }
#pragma unroll
    for (int o = 32; o > 0; o >>= 1) d2 += __shfl_down(d2, o);
    __shared__ float wsum[4];
    if ((threadIdx.x & 63) == 0) wsum[threadIdx.x >> 6] = d2;
    __syncthreads();
    if (threadIdx.x == 0)
        atomicAdd(loss_sum, (double)(wsum[0] + wsum[1] + wsum[2] + wsum[3]));
}

__global__ __launch_bounds__(512)
void vq_finalize(const float* __restrict__ counts, const double* __restrict__ loss_sum,
                 float* __restrict__ out, int Ntot, int Npts)
{
    int t = threadIdx.x;
    float c   = counts[t];
    float avg = c / (float)Npts;
    float term = avg * logf(avg + 1e-10f);
#pragma unroll
    for (int o = 32; o > 0; o >>= 1) term += __shfl_down(term, o);
    __shared__ float wsum[8];
    if ((t & 63) == 0) wsum[t >> 6] = term;
    __syncthreads();
    if (t == 0) {
        float s = 0.0f;
        for (int i = 0; i < 8; ++i) s += wsum[i];
        out[Ntot]     = 0.25f * (float)(loss_sum[0] / (double)Ntot);
        out[Ntot + 1] = expf(-s);
    }
}

// ================================ launcher ==================================
extern "C" void kernel_launch(void* const* d_in, const int* in_sizes, int n_in,
                              void* d_out, int out_size, void* d_ws, size_t ws_size,
                              hipStream_t stream)
{
    const float* mels     = (const float*)d_in[0];
    const float* w1       = (const float*)d_in[1];
    const float* w2       = (const float*)d_in[2];
    const float* w3       = (const float*)d_in[3];
    const float* w4       = (const float*)d_in[4];
    const float* w5       = (const float*)d_in[5];
    const float* w6       = (const float*)d_in[6];
    const float* b6       = (const float*)d_in[7];
    const float* bn_gamma = (const float*)d_in[8];
    const float* bn_beta  = (const float*)d_in[9];
    const float* bn_mean  = (const float*)d_in[10];
    const float* bn_var   = (const float*)d_in[11];
    const float* emb      = (const float*)d_in[12];

    constexpr int B = 32, C = 768, D = 64, T2 = 511;

    char* ws = (char*)d_ws;
    unsigned* P1 = (unsigned*)ws;                      // 100,663,296 B
    unsigned* P2 = (unsigned*)(ws + 100663296);        // 100,663,296 B
    unsigned* Wp = (unsigned*)(ws + 201326592);        // 9,437,184 B (max: conv3)
    size_t misc  = 201326592 + 9437184;
    float*  counts = (float*)(ws + misc);              // 2048 B
    double* lossp  = (double*)(ws + misc + 2048);      // 8 B (+pad)
    float*  e2p    = (float*)(ws + misc + 2048 + 64);  // 2048 B
    int*    idx    = (int*)(ws + misc + 2048 + 64 + 2048);  // 65,408 B

    unsigned* melsT = P2;                              // alias (dead before conv2 out)
    float*    bufA  = (float*)P1;                      // conv5 fp32 out (x3 dead)
    float*    z     = (float*)P2;                      // conv6 out (x4 dead)

    hipMemsetAsync(ws + misc, 0, 2048 + 64, stream);   // counts + loss

    vq_e2<<<dim3(2), 256, 0, stream>>>(emb, e2p);
    prep_mels<<<dim3((32 * 1032 * 96 + 255) / 256), 256, 0, stream>>>(mels, melsT);

    // conv1: Cin 80 (pad 96), KW 3, S1 P0, in melsT[1032][96] -> x1 = P1 [1024][768]
    prep_w<<<dim3((3 * 768 * 96 + 255) / 256), 256, 0, stream>>>(w1, Wp, 80, 3, 96);
    conv_mfma<3, 1, 0, 96, 1032, 1032, 1022, 1024, 0><<<dim3(6, 8, B), 256, 0, stream>>>(
        melsT, Wp, bn_gamma + 0 * C, bn_beta + 0 * C, bn_mean + 0 * C, bn_var + 0 * C, P1, nullptr);
    // conv2: x1(P1) -> x2(P2)
    prep_w<<<dim3((3 * 768 * 768 + 255) / 256), 256, 0, stream>>>(w2, Wp, 768, 3, 768);
    conv_mfma<3, 1, 1, 768, 1022, 1024, 1022, 1024, 0><<<dim3(6, 8, B), 256, 0, stream>>>(
        P1, Wp, bn_gamma + 1 * C, bn_beta + 1 * C, bn_mean + 1 * C, bn_var + 1 * C, P2, nullptr);
    // conv3: stride 2, KW 4: x2(P2) -> x3(P1, stride 512)
    prep_w<<<dim3((4 * 768 * 768 + 255) / 256), 256, 0, stream>>>(w3, Wp, 768, 4, 768);
    conv_mfma<4, 2, 1, 768, 1022, 1024, 511, 512, 0><<<dim3(6, 4, B), 256, 0, stream>>>(
        P2, Wp, bn_gamma + 2 * C, bn_beta + 2 * C, bn_mean + 2 * C, bn_var + 2 * C, P1, nullptr);
    // conv4: x3(P1) -> x4(P2)
    prep_w<<<dim3((3 * 768 * 768 + 255) / 256), 256, 0, stream>>>(w4, Wp, 768, 3, 768);
    conv_mfma<3, 1, 1, 768, 511, 512, 511, 512, 0><<<dim3(6, 4, B), 256, 0, stream>>>(
        P1, Wp, bn_gamma + 3 * C, bn_beta + 3 * C, bn_mean + 3 * C, bn_var + 3 * C, P2, nullptr);
    // conv5: x4(P2) -> bufA fp32 [768][511] (EPI=1)
    prep_w<<<dim3((3 * 768 * 768 + 255) / 256), 256, 0, stream>>>(w5, Wp, 768, 3, 768);
    conv_mfma<3, 1, 1, 768, 511, 512, 511, 511, 1><<<dim3(6, 4, B), 256, 0, stream>>>(
        P2, Wp, bn_gamma + 4 * C, bn_beta + 4 * C, bn_mean + 4 * C, bn_var + 4 * C, nullptr, bufA);

    conv1x1_bias_T<<<dim3(1, 8, B), 256, 0, stream>>>(bufA, w6, b6, z, C, T2);

    const int Npts = B * T2;
    const int Ntot = Npts * D;
    vq_argmin<<<dim3((Npts + 63) / 64), 64, 0, stream>>>(z, emb, e2p, idx, counts, Npts);
    vq_quant_loss<<<dim3(Ntot / 256), 256, 0, stream>>>(z, emb, idx, (float*)d_out, lossp, Ntot);
    vq_finalize<<<dim3(1), 512, 0, stream>>>(counts, lossp, (float*)d_out, Ntot, Npts);
}

// Round 9
// 1719.407 us; speedup vs baseline: 2.7165x; 2.7165x over previous
//
#include <hip/hip_runtime.h>
#include <cstddef>
#include <cstdint>

#define BN_EPS 1e-5f

typedef _Float16 half8 __attribute__((ext_vector_type(8)));
typedef float f32x4v __attribute__((ext_vector_type(4)));

// pack fp32 (pre-scaled) into fp16 high/low split: v = h + l/2048
__device__ __forceinline__ unsigned split_pack(float v) {
    _Float16 h = (_Float16)v;
    float r = (v - (float)h) * 2048.0f;
    _Float16 l = (_Float16)r;
    unsigned short hu = __builtin_bit_cast(unsigned short, h);
    unsigned short lu = __builtin_bit_cast(unsigned short, l);
    return (unsigned)hu | ((unsigned)lu << 16);
}

// ===== prep: w[co][ci][kw] fp32 -> Wp[kw][co][CIPAD] packed u32, scaled x256
__global__ __launch_bounds__(256)
void prep_w(const float* __restrict__ w, unsigned* __restrict__ wp,
            int Cin, int KW, int CIPAD)
{
    int id = blockIdx.x * 256 + threadIdx.x;
    int total = KW * 768 * CIPAD;
    if (id >= total) return;
    int cip = id % CIPAD;
    int co  = (id / CIPAD) % 768;
    int kw  = id / (CIPAD * 768);
    float v = 0.0f;
    if (cip < Cin) v = w[((size_t)co * Cin + cip) * KW + kw];
    wp[id] = split_pack(v * 256.0f);
}

// ===== prep: mels[b][80][1024] fp32 -> melsT[b][1032][96] packed, scaled x16
__global__ __launch_bounds__(256)
void prep_mels(const float* __restrict__ mels, unsigned* __restrict__ mt)
{
    int id = blockIdx.x * 256 + threadIdx.x;
    if (id >= 32 * 1032 * 96) return;
    int c = id % 96;
    int t = (id / 96) % 1032;
    int b = id / (96 * 1032);
    float v = 0.0f;
    if (c < 80 && t < 1024) v = mels[((size_t)b * 80 + c) * 1024 + t];
    mt[id] = split_pack(v * 16.0f);
}

// ===== fp16x3-split MFMA conv + BN + ReLU =====================================
// Block 256 thr (4 waves), tile 128co x 128t, wave tile 64x64 (4x4 of 16x16x32).
// A = weights (scale 256), B = activations (scale 16), both packed h|l u32.
// result = (accHH + accCROSS/2048)/4096.
// C/D layout (m89-verified): col(n)=lane&15, row(m)=quad*4+reg.
// R9: MFMA-order LDS planes [tile16][kquad][l16][8] -> frag reads and staging
// writes are both lane-contiguous b128 (conflict-free by construction).
// Double-buffered LDS, ONE reg set: store(c+1); load(c+2); compute(c); barrier.
// (R8's 2-deep prefetch = 64 extra VGPRs -> scratch spill, 4.2 GB HBM traffic.)
// EPI=0: write packed [t][768] u32; EPI=1 (conv5): write fp32 [co][TOUT].
template<int KW, int S, int P, int CIPAD, int TIN, int TSIN, int TOUT, int TSOUT, int EPI>
__global__ __launch_bounds__(256)
void conv_mfma(const unsigned* __restrict__ Xin, const unsigned* __restrict__ Wp,
               const float* __restrict__ gamma, const float* __restrict__ beta,
               const float* __restrict__ mean, const float* __restrict__ var,
               unsigned* __restrict__ Uout, float* __restrict__ Fout)
{
    constexpr int NCI = CIPAD / 32;
    constexpr int NC  = KW * NCI;          // >= 9 for all convs
    __shared__ unsigned smem[16896];       // 67584 B: planes 2x32KB; bounce [128][132]
    _Float16* sm = (_Float16*)smem;
    // per-buffer plane offsets (halfs): AH 0, AL 4096, BH 8192, BL 12288; buf stride 16384
    // plane layout: 16B-unit u = (tile16*4 + kquad)*16 + l16  (tile16 = row>>4, l16 = row&15)

    const int b   = blockIdx.z;
    const int co0 = blockIdx.x * 128;
    const int t0  = blockIdx.y * 128;
    const int tid = threadIdx.x;
    const int lane = tid & 63, wv = tid >> 6;
    const int quad = lane >> 4, l16 = lane & 15;
    const int wm = (wv & 1) * 64, wn = (wv >> 1) * 64;

    f32x4v accH[4][4] = {};
    f32x4v accX[4][4] = {};

    const int srow = tid >> 1;             // 0..127: row staged by this thread
    const int sh   = tid & 1;              // owns k-quads {sh, sh+2}
    const unsigned* __restrict__ xb = Xin + (size_t)b * TSIN * CIPAD;

    uint4 rA[4], rB[4];

    auto loadAB = [&](int c) {
        const int kw  = c / NCI;
        const int ci0 = (c % NCI) * 32;
        const unsigned* pA = Wp + (size_t)(kw * 768 + co0 + srow) * CIPAD + ci0;
        rA[0] = *(const uint4*)(pA + sh * 8);
        rA[1] = *(const uint4*)(pA + sh * 8 + 4);
        rA[2] = *(const uint4*)(pA + (sh + 2) * 8);
        rA[3] = *(const uint4*)(pA + (sh + 2) * 8 + 4);
        const int tp = (t0 + srow) * S + kw - P;
        rB[0] = rB[1] = rB[2] = rB[3] = make_uint4(0, 0, 0, 0);
        if ((unsigned)tp < (unsigned)TIN) {
            const unsigned* pB = xb + (size_t)tp * CIPAD + ci0;
            rB[0] = *(const uint4*)(pB + sh * 8);
            rB[1] = *(const uint4*)(pB + sh * 8 + 4);
            rB[2] = *(const uint4*)(pB + (sh + 2) * 8);
            rB[3] = *(const uint4*)(pB + (sh + 2) * 8 + 4);
        }
    };

    auto splitHL = [](uint4 a, uint4 b2, uint4& h, uint4& l) {
        h.x = (a.x & 0xffffu) | (a.y << 16);
        h.y = (a.z & 0xffffu) | (a.w << 16);
        h.z = (b2.x & 0xffffu) | (b2.y << 16);
        h.w = (b2.z & 0xffffu) | (b2.w << 16);
        l.x = (a.x >> 16) | (a.y & 0xffff0000u);
        l.y = (a.z >> 16) | (a.w & 0xffff0000u);
        l.z = (b2.x >> 16) | (b2.y & 0xffff0000u);
        l.w = (b2.z >> 16) | (b2.w & 0xffff0000u);
    };

    auto storeAB = [&](int pbuf) {
        const int b0 = pbuf * 16384;
        const int u1 = (((srow >> 4) * 4 + sh) * 16 + (srow & 15)) * 8;  // halfs
        const int u2 = u1 + 256;                                          // q = sh+2
        uint4 h, l;
        splitHL(rA[0], rA[1], h, l);
        *(uint4*)(sm + b0 + 0     + u1) = h;
        *(uint4*)(sm + b0 + 4096  + u1) = l;
        splitHL(rA[2], rA[3], h, l);
        *(uint4*)(sm + b0 + 0     + u2) = h;
        *(uint4*)(sm + b0 + 4096  + u2) = l;
        splitHL(rB[0], rB[1], h, l);
        *(uint4*)(sm + b0 + 8192  + u1) = h;
        *(uint4*)(sm + b0 + 12288 + u1) = l;
        splitHL(rB[2], rB[3], h, l);
        *(uint4*)(sm + b0 + 8192  + u2) = h;
        *(uint4*)(sm + b0 + 12288 + u2) = l;
    };

    loadAB(0);
    storeAB(0);
    if (NC > 1) loadAB(1);
    __syncthreads();

    int p = 0;
    for (int c = 0; c < NC; ++c) {
        const int base = p * 16384;
        if (c + 1 < NC) storeAB(p ^ 1);    // drains reg set into other buffer
        if (c + 2 < NC) loadAB(c + 2);     // refills reg set; covered by compute(c)

        half8 bh[4], bl[4];
#pragma unroll
        for (int nt = 0; nt < 4; ++nt) {
            int gn = (wv >> 1) * 4 + nt;
            int u = ((gn * 4 + quad) * 16 + l16) * 8;
            bh[nt] = *(const half8*)(sm + base + 8192  + u);
            bl[nt] = *(const half8*)(sm + base + 12288 + u);
        }
#pragma unroll
        for (int mt = 0; mt < 4; ++mt) {
            int gm = (wv & 1) * 4 + mt;
            int u = ((gm * 4 + quad) * 16 + l16) * 8;
            half8 ah = *(const half8*)(sm + base + 0    + u);
            half8 al = *(const half8*)(sm + base + 4096 + u);
#pragma unroll
            for (int nt = 0; nt < 4; ++nt) {
                accH[mt][nt] = __builtin_amdgcn_mfma_f32_16x16x32_f16(ah, bh[nt], accH[mt][nt], 0, 0, 0);
                accX[mt][nt] = __builtin_amdgcn_mfma_f32_16x16x32_f16(ah, bl[nt], accX[mt][nt], 0, 0, 0);
                accX[mt][nt] = __builtin_amdgcn_mfma_f32_16x16x32_f16(al, bh[nt], accX[mt][nt], 0, 0, 0);
            }
        }
        __syncthreads();                   // reads of p + stores to p^1 drained
        p ^= 1;
    }

    if constexpr (EPI == 0) {
        unsigned* bb = smem;                       // bounce: [t_local][co_local], stride 132
#pragma unroll
        for (int mt = 0; mt < 4; ++mt) {
#pragma unroll
            for (int r = 0; r < 4; ++r) {
                int mloc = wm + mt * 16 + quad * 4 + r;   // C/D row = co_local
                int co = co0 + mloc;
                float iv = gamma[co] / sqrtf(var[co] + BN_EPS);
                float sh2 = beta[co] - mean[co] * iv;
#pragma unroll
                for (int nt = 0; nt < 4; ++nt) {
                    float vf = (accH[mt][nt][r] + accX[mt][nt][r] * (1.0f / 2048.0f)) * (1.0f / 4096.0f);
                    float y = fmaf(vf, iv, sh2);
                    y = y > 0.0f ? y : 0.0f;
                    bb[(wn + nt * 16 + l16) * 132 + mloc] = split_pack(y * 16.0f);
                }
            }
        }
        __syncthreads();
        int tl = tid >> 1, seg = tid & 1;
        int t = t0 + tl;
        if (t < TOUT) {
            uint4* dst = (uint4*)(Uout + ((size_t)b * TSOUT + t) * 768 + co0 + seg * 64);
            const uint4* src = (const uint4*)(bb + tl * 132 + seg * 64);
#pragma unroll
            for (int i = 0; i < 16; ++i) dst[i] = src[i];
        }
    } else {
#pragma unroll
        for (int mt = 0; mt < 4; ++mt) {
#pragma unroll
            for (int r = 0; r < 4; ++r) {
                int co = co0 + wm + mt * 16 + quad * 4 + r;
                float iv = gamma[co] / sqrtf(var[co] + BN_EPS);
                float sh2 = beta[co] - mean[co] * iv;
                float* op = Fout + ((size_t)b * 768 + co) * TOUT;
#pragma unroll
                for (int nt = 0; nt < 4; ++nt) {
                    int t = t0 + wn + nt * 16 + l16;
                    if (t < TOUT) {
                        float vf = (accH[mt][nt][r] + accX[mt][nt][r] * (1.0f / 2048.0f)) * (1.0f / 4096.0f);
                        float y = fmaf(vf, iv, sh2);
                        op[t] = y > 0.0f ? y : 0.0f;
                    }
                }
            }
        }
    }
}

// ================= 1x1 conv (C=768 -> D=64) + bias, output z[b][t][d] =======
constexpr int TM = 64, TN = 64, TK = 16;

__global__ __launch_bounds__(256)
void conv1x1_bias_T(const float* __restrict__ in, const float* __restrict__ w,
                    const float* __restrict__ bias, float* __restrict__ z,
                    int Cin, int T)
{
    const int b   = blockIdx.z;
    const int t0  = blockIdx.y * TN;
    const int tid = threadIdx.x;

    __shared__ float As[TK][TM + 4];
    __shared__ float Bs[TK][TN + 4];

    float acc[4][4] = {};

    const int m0 = (tid & 15) * 4;
    const int n0 = (tid >> 4) * 4;

    const float* __restrict__ inb = in + (size_t)b * Cin * T;

    const int a_m = tid >> 4;
    const int a_k = tid & 15;
    const int b_k = tid >> 6;
    const int b_n = tid & 63;

    for (int kc = 0; kc < Cin; kc += TK) {
        __syncthreads();
#pragma unroll
        for (int i = 0; i < 4; ++i) {
            int m = a_m + 16 * i;
            As[a_k][m] = w[(size_t)m * Cin + kc + a_k];
        }
#pragma unroll
        for (int i = 0; i < 4; ++i) {
            int kk = b_k + 4 * i;
            int ci = kc + kk;
            int t  = t0 + b_n;
            Bs[kk][b_n] = (t < T) ? inb[(size_t)ci * T + t] : 0.0f;
        }
        __syncthreads();
#pragma unroll
        for (int kk = 0; kk < TK; ++kk) {
            float4 av = *reinterpret_cast<const float4*>(&As[kk][m0]);
            float4 bv = *reinterpret_cast<const float4*>(&Bs[kk][n0]);
            float am[4] = {av.x, av.y, av.z, av.w};
            float bn[4] = {bv.x, bv.y, bv.z, bv.w};
#pragma unroll
            for (int mi = 0; mi < 4; ++mi)
#pragma unroll
                for (int nj = 0; nj < 4; ++nj)
                    acc[mi][nj] = fmaf(am[mi], bn[nj], acc[mi][nj]);
        }
    }

    float4 bb = *reinterpret_cast<const float4*>(&bias[m0]);
    float bs[4] = {bb.x, bb.y, bb.z, bb.w};
#pragma unroll
    for (int nj = 0; nj < 4; ++nj) {
        int t = t0 + n0 + nj;
        if (t < T) {
            float4 v;
            v.x = acc[0][nj] + bs[0];
            v.y = acc[1][nj] + bs[1];
            v.z = acc[2][nj] + bs[2];
            v.w = acc[3][nj] + bs[3];
            *reinterpret_cast<float4*>(&z[((size_t)b * T + t) * 64 + m0]) = v;
        }
    }
}

// ============================== VQ kernels ==================================
__global__ __launch_bounds__(256)
void vq_e2(const float* __restrict__ emb, float* __restrict__ e2)
{
    int m = blockIdx.x * 256 + threadIdx.x;
    if (m < 512) {
        float s = 0.0f;
#pragma unroll
        for (int d = 0; d < 64; ++d) {
            float v = emb[(size_t)m * 64 + d];
            s = fmaf(v, v, s);
        }
        e2[m] = s;
    }
}

__global__ __launch_bounds__(64)
void vq_argmin(const float* __restrict__ z, const float* __restrict__ emb,
               const float* __restrict__ e2, int* __restrict__ idx,
               float* __restrict__ counts, int N)
{
    __shared__ float Es[64 * 64];
    const int tid = threadIdx.x;
    const int n   = blockIdx.x * 64 + tid;
    const bool act = n < N;

    float x[64];
    float x2 = 0.0f;
    if (act) {
        const float4* zp = reinterpret_cast<const float4*>(z + (size_t)n * 64);
#pragma unroll
        for (int i = 0; i < 16; ++i) {
            float4 v = zp[i];
            x[4 * i + 0] = v.x; x[4 * i + 1] = v.y;
            x[4 * i + 2] = v.z; x[4 * i + 3] = v.w;
        }
#pragma unroll
        for (int d = 0; d < 64; ++d) x2 = fmaf(x[d], x[d], x2);
    }

    float best = 3.4e38f;
    int   bi   = 0;
    for (int c = 0; c < 8; ++c) {
        __syncthreads();
        const float4* ep  = reinterpret_cast<const float4*>(emb + (size_t)c * 4096);
        float4*       esp = reinterpret_cast<float4*>(Es);
#pragma unroll
        for (int i = 0; i < 16; ++i) esp[tid + 64 * i] = ep[tid + 64 * i];
        __syncthreads();
        for (int r = 0; r < 64; ++r) {
            const float4* er = reinterpret_cast<const float4*>(&Es[r * 64]);
            float dot = 0.0f;
#pragma unroll
            for (int i = 0; i < 16; ++i) {
                float4 e4 = er[i];
                dot = fmaf(x[4 * i + 0], e4.x, dot);
                dot = fmaf(x[4 * i + 1], e4.y, dot);
                dot = fmaf(x[4 * i + 2], e4.z, dot);
                dot = fmaf(x[4 * i + 3], e4.w, dot);
            }
            float dist = (e2[c * 64 + r] + x2) - 2.0f * dot;  // reference op order
            if (dist < best) { best = dist; bi = c * 64 + r; }
        }
    }
    if (act) {
        idx[n] = bi;
        atomicAdd(&counts[bi], 1.0f);
    }
}

__global__ __launch_bounds__(256)
void vq_quant_loss(const float* __restrict__ z, const float* __restrict__ emb,
                   const int* __restrict__ idx, float* __restrict__ qout,
                   double* __restrict__ loss_sum, int Ntot)
{
    int g = blockIdx.x * 256 + threadIdx.x;
    float d2 = 0.0f;
    if (g < Ntot) {
        int n = g >> 6;
        int d = g & 63;
        float q  = emb[(size_t)idx[n] * 64 + d];
        float zv = z[g];
        qout[g] = zv + (q - zv);
        float diff = zv - q;
        d2 = diff * diff;
    }
#pragma unroll
    for (int o = 32; o > 0; o >>= 1) d2 += __shfl_down(d2, o);
    __shared__ float wsum[4];
    if ((threadIdx.x & 63) == 0) wsum[threadIdx.x >> 6] = d2;
    __syncthreads();
    if (threadIdx.x == 0)
        atomicAdd(loss_sum, (double)(wsum[0] + wsum[1] + wsum[2] + wsum[3]));
}

__global__ __launch_bounds__(512)
void vq_finalize(const float* __restrict__ counts, const double* __restrict__ loss_sum,
                 float* __restrict__ out, int Ntot, int Npts)
{
    int t = threadIdx.x;
    float c   = counts[t];
    float avg = c / (float)Npts;
    float term = avg * logf(avg + 1e-10f);
#pragma unroll
    for (int o = 32; o > 0; o >>= 1) term += __shfl_down(term, o);
    __shared__ float wsum[8];
    if ((t & 63) == 0) wsum[t >> 6] = term;
    __syncthreads();
    if (t == 0) {
        float s = 0.0f;
        for (int i = 0; i < 8; ++i) s += wsum[i];
        out[Ntot]     = 0.25f * (float)(loss_sum[0] / (double)Ntot);
        out[Ntot + 1] = expf(-s);
    }
}

// ================================ launcher ==================================
extern "C" void kernel_launch(void* const* d_in, const int* in_sizes, int n_in,
                              void* d_out, int out_size, void* d_ws, size_t ws_size,
                              hipStream_t stream)
{
    const float* mels     = (const float*)d_in[0];
    const float* w1       = (const float*)d_in[1];
    const float* w2       = (const float*)d_in[2];
    const float* w3       = (const float*)d_in[3];
    const float* w4       = (const float*)d_in[4];
    const float* w5       = (const float*)d_in[5];
    const float* w6       = (const float*)d_in[6];
    const float* b6       = (const float*)d_in[7];
    const float* bn_gamma = (const float*)d_in[8];
    const float* bn_beta  = (const float*)d_in[9];
    const float* bn_mean  = (const float*)d_in[10];
    const float* bn_var   = (const float*)d_in[11];
    const float* emb      = (const float*)d_in[12];

    constexpr int B = 32, C = 768, D = 64, T2 = 511;

    char* ws = (char*)d_ws;
    unsigned* P1 = (unsigned*)ws;                      // 100,663,296 B
    unsigned* P2 = (unsigned*)(ws + 100663296);        // 100,663,296 B
    unsigned* Wp = (unsigned*)(ws + 201326592);        // 9,437,184 B (max: conv3)
    size_t misc  = 201326592 + 9437184;
    float*  counts = (float*)(ws + misc);              // 2048 B
    double* lossp  = (double*)(ws + misc + 2048);      // 8 B (+pad)
    float*  e2p    = (float*)(ws + misc + 2048 + 64);  // 2048 B
    int*    idx    = (int*)(ws + misc + 2048 + 64 + 2048);  // 65,408 B

    unsigned* melsT = P2;                              // alias (dead before conv2 out)
    float*    bufA  = (float*)P1;                      // conv5 fp32 out (x3 dead)
    float*    z     = (float*)P2;                      // conv6 out (x4 dead)

    hipMemsetAsync(ws + misc, 0, 2048 + 64, stream);   // counts + loss

    vq_e2<<<dim3(2), 256, 0, stream>>>(emb, e2p);
    prep_mels<<<dim3((32 * 1032 * 96 + 255) / 256), 256, 0, stream>>>(mels, melsT);

    // conv1: Cin 80 (pad 96), KW 3, S1 P0, in melsT[1032][96] -> x1 = P1 [1024][768]
    prep_w<<<dim3((3 * 768 * 96 + 255) / 256), 256, 0, stream>>>(w1, Wp, 80, 3, 96);
    conv_mfma<3, 1, 0, 96, 1032, 1032, 1022, 1024, 0><<<dim3(6, 8, B), 256, 0, stream>>>(
        melsT, Wp, bn_gamma + 0 * C, bn_beta + 0 * C, bn_mean + 0 * C, bn_var + 0 * C, P1, nullptr);
    // conv2: x1(P1) -> x2(P2)
    prep_w<<<dim3((3 * 768 * 768 + 255) / 256), 256, 0, stream>>>(w2, Wp, 768, 3, 768);
    conv_mfma<3, 1, 1, 768, 1022, 1024, 1022, 1024, 0><<<dim3(6, 8, B), 256, 0, stream>>>(
        P1, Wp, bn_gamma + 1 * C, bn_beta + 1 * C, bn_mean + 1 * C, bn_var + 1 * C, P2, nullptr);
    // conv3: stride 2, KW 4: x2(P2) -> x3(P1, stride 512)
    prep_w<<<dim3((4 * 768 * 768 + 255) / 256), 256, 0, stream>>>(w3, Wp, 768, 4, 768);
    conv_mfma<4, 2, 1, 768, 1022, 1024, 511, 512, 0><<<dim3(6, 4, B), 256, 0, stream>>>(
        P2, Wp, bn_gamma + 2 * C, bn_beta + 2 * C, bn_mean + 2 * C, bn_var + 2 * C, P1, nullptr);
    // conv4: x3(P1) -> x4(P2)
    prep_w<<<dim3((3 * 768 * 768 + 255) / 256), 256, 0, stream>>>(w4, Wp, 768, 3, 768);
    conv_mfma<3, 1, 1, 768, 511, 512, 511, 512, 0><<<dim3(6, 4, B), 256, 0, stream>>>(
        P1, Wp, bn_gamma + 3 * C, bn_beta + 3 * C, bn_mean + 3 * C, bn_var + 3 * C, P2, nullptr);
    // conv5: x4(P2) -> bufA fp32 [768][511] (EPI=1)
    prep_w<<<dim3((3 * 768 * 768 + 255) / 256), 256, 0, stream>>>(w5, Wp, 768, 3, 768);
    conv_mfma<3, 1, 1, 768, 511, 512, 511, 511, 1><<<dim3(6, 4, B), 256, 0, stream>>>(
        P2, Wp, bn_gamma + 4 * C, bn_beta + 4 * C, bn_mean + 4 * C, bn_var + 4 * C, nullptr, bufA);

    conv1x1_bias_T<<<dim3(1, 8, B), 256, 0, stream>>>(bufA, w6, b6, z, C, T2);

    const int Npts = B * T2;
    const int Ntot = Npts * D;
    vq_argmin<<<dim3((Npts + 63) / 64), 64, 0, stream>>>(z, emb, e2p, idx, counts, Npts);
    vq_quant_loss<<<dim3(Ntot / 256), 256, 0, stream>>>(z, emb, idx, (float*)d_out, lossp, Ntot);
    vq_finalize<<<dim3(1), 512, 0, stream>>>(counts, lossp, (float*)d_out, Ntot, Npts);
}